// Round 5
// baseline (194.015 us; speedup 1.0000x reference)
//
#include <hip/hip_runtime.h>

#define NN 8192

typedef float f32x4 __attribute__((ext_vector_type(4)));

// Kernel 1: PURE READ. Per-row sum -> d[row] = rsqrt(sum) (inf->0).
// Seeds L3 with all of A with no write interference.
__global__ __launch_bounds__(256) void rowsum_kernel(
    const float* __restrict__ A, float* __restrict__ d) {
    const int row = blockIdx.x;
    const f32x4* Arow = reinterpret_cast<const f32x4*>(A + (size_t)row * NN);
    f32x4 v[8];
    #pragma unroll
    for (int u = 0; u < 8; ++u)
        v[u] = Arow[threadIdx.x + 256 * u];
    float s = 0.f;
    #pragma unroll
    for (int u = 0; u < 8; ++u)
        s += (v[u].x + v[u].y) + (v[u].z + v[u].w);
    #pragma unroll
    for (int off = 32; off > 0; off >>= 1)
        s += __shfl_down(s, off, 64);
    __shared__ float ls[4];
    const int lane = threadIdx.x & 63;
    const int wid  = threadIdx.x >> 6;
    if (lane == 0) ls[wid] = s;
    __syncthreads();
    if (threadIdx.x == 0) {
        float t = (ls[0] + ls[1]) + (ls[2] + ls[3]);
        d[row] = (t > 0.f) ? (1.0f / sqrtf(t)) : 0.f;
    }
}

// Kernel 2: PURE HBM WRITE (A read hits L3). Builds Lfilter (= DAD),
// Hfilter (= 2I - DAD), Graph_adj passthrough. 4 f32x4/thread in 256-apart
// chunks -> each block covers a 16 KB contiguous run per output stream
// (longer DRAM bursts, fewer page opens). All A-loads issued before stores.
// Non-temporal stores keep A resident in L3. Block order reversed to read
// the most recently cached rows first.
__global__ __launch_bounds__(256) void build_filters_kernel(
    const float* __restrict__ A, const float* __restrict__ d,
    float* __restrict__ lf, float* __restrict__ hf, float* __restrict__ ga,
    int nblocks) {
    const size_t base = (size_t)(nblocks - 1 - blockIdx.x) * 1024; // f32x4 units
    const int i = (int)(base >> 11);   // row (1024 | 2048 -> uniform per block)
    const float di = d[i];             // block-uniform scalar load

    const f32x4* A4 = reinterpret_cast<const f32x4*>(A);
    const f32x4* d4 = reinterpret_cast<const f32x4*>(d);

    size_t idx[4];
    f32x4 a[4], dj[4];
    #pragma unroll
    for (int u = 0; u < 4; ++u) {
        idx[u] = base + threadIdx.x + 256 * u;
        a[u] = A4[idx[u]];             // burst: 4 loads in flight
    }
    #pragma unroll
    for (int u = 0; u < 4; ++u)
        dj[u] = d4[idx[u] & 2047];

    f32x4 dad[4], h[4];
    #pragma unroll
    for (int u = 0; u < 4; ++u) {
        dad[u] = di * a[u] * dj[u];
        const int j = (int)(idx[u] & 2047) * 4;
        h[u].x = ((j + 0) == i ? 2.0f : 0.0f) - dad[u].x;
        h[u].y = ((j + 1) == i ? 2.0f : 0.0f) - dad[u].y;
        h[u].z = ((j + 2) == i ? 2.0f : 0.0f) - dad[u].z;
        h[u].w = ((j + 3) == i ? 2.0f : 0.0f) - dad[u].w;
    }

    f32x4* lf4 = reinterpret_cast<f32x4*>(lf);
    f32x4* hf4 = reinterpret_cast<f32x4*>(hf);
    f32x4* ga4 = reinterpret_cast<f32x4*>(ga);
    #pragma unroll
    for (int u = 0; u < 4; ++u)
        __builtin_nontemporal_store(dad[u], &lf4[idx[u]]);
    #pragma unroll
    for (int u = 0; u < 4; ++u)
        __builtin_nontemporal_store(h[u], &hf4[idx[u]]);
    #pragma unroll
    for (int u = 0; u < 4; ++u)
        __builtin_nontemporal_store(a[u], &ga4[idx[u]]);
}

extern "C" void kernel_launch(void* const* d_in, const int* in_sizes, int n_in,
                              void* d_out, int out_size, void* d_ws, size_t ws_size,
                              hipStream_t stream) {
    const float* A = (const float*)d_in[0];
    float* out = (float*)d_out;
    const size_t M = (size_t)NN * NN;
    float* lf = out;           // Lfilter = DAD
    float* hf = out + M;       // Hfilter = 2I - DAD
    float* ga = out + 2 * M;   // Graph_adj passthrough
    float* d  = (float*)d_ws;  // 8192 floats

    rowsum_kernel<<<NN, 256, 0, stream>>>(A, d);

    const int nblocks = (int)(M / 4 / 1024);  // 16384
    build_filters_kernel<<<nblocks, 256, 0, stream>>>(A, d, lf, hf, ga, nblocks);
}